// Round 1
// 822.875 us; speedup vs baseline: 1.2292x; 1.2292x over previous
//
#include <hip/hip_runtime.h>
#include <hip/hip_bf16.h>

#define B_ 32
#define P_ 1024
#define F_ 512
#define C_ 512

#define BM 128
#define BN 128
#define BK 64

typedef unsigned short u16;
typedef unsigned int   u32;
typedef __bf16 bf16x8 __attribute__((ext_vector_type(8)));
typedef float  f32x4  __attribute__((ext_vector_type(4)));

union U4 { uint4 v; u16 h[8]; u32 w[4]; };

__device__ __forceinline__ u16 f2bf(float f) {
  u32 x = __builtin_bit_cast(u32, f);
  return (u16)((x + 0x7FFFu + ((x >> 16) & 1u)) >> 16);   // RNE
}
__device__ __forceinline__ u32 pack2(float a, float b) {
  return (u32)f2bf(a) | ((u32)f2bf(b) << 16);
}

__device__ __forceinline__ f32x4 mfma16(bf16x8 a, bf16x8 b, f32x4 c) {
  return __builtin_amdgcn_mfma_f32_16x16x32_bf16(a, b, c, 0, 0, 0);
}

// 16B-chunk XOR swizzle for a [rows][64] bf16 tile: logical chunk c (k = c*8..c*8+7)
// of row m lives at chunk index m*8 + (c ^ (m&7)).  Rows are 128 B; the XOR spreads
// the 16 lanes of a fragment read (rows m..m+15, same c) across all 32 banks.
__device__ __forceinline__ int swzc(int m, int c) { return m * 8 + (c ^ (m & 7)); }

// async global->LDS, 16 B per lane; dest = wave-uniform base + lane*16
__device__ __forceinline__ void gload16(const u16* g, u16* l) {
  __builtin_amdgcn_global_load_lds((const __attribute__((address_space(1))) void*)(g),
                                   (__attribute__((address_space(3))) void*)(l), 16, 0, 0);
}

// ---------------------------------------------------------------- out0 / out2
// x: f32 [B,P,F] -> f32 copy (out0) and 3x broadcast (out2). Pure BW.
__global__ __launch_bounds__(256) void copy_kernel(const uint4* __restrict__ x,
                                                   uint4* __restrict__ out0,
                                                   uint4* __restrict__ out2) {
  int i = blockIdx.x * 256 + threadIdx.x;       // float4 group, [0, B*P*F/4)
  uint4 v = x[i];
  out0[i] = v;
  int b = i >> 17;                              // P*F/4 = 131072 groups per graph
  int r = i & 131071;
  uint4* o2 = out2 + ((size_t)b * 3 * 131072 + r);
  o2[0] = v; o2[131072] = v; o2[2 * 131072] = v;
}

// ---------------------------------------------------------------- out3 gather/transpose
// out3[b,c,p] = evec[b,p, round(c*step)]  (f32 in, f32 out)
__global__ __launch_bounds__(256) void sel_kernel(const float* __restrict__ evec,
                                                  const int* __restrict__ nv,
                                                  float* __restrict__ out3) {
  const int b  = blockIdx.z;
  const int c0 = blockIdx.y * 64;
  const int p0 = blockIdx.x * 64;
  const int N  = nv[b];
  const float step = (float)(N - 1) / 511.0f;               // (C-1)=511, f32 like jnp
  const int base  = (int)rintf((float)c0 * step);
  const int basea = base & ~3;                               // float4-aligned window start
  __shared__ float tile[64][145];                            // 144-col window, odd stride
  const int t = threadIdx.x;

  for (int it = t; it < 64 * 36; it += 256) {                // 64 rows x 36 groups of 4
    int row = it / 36, g = it % 36;
    int colg = basea + g * 4;
    const float* src = evec + ((size_t)b * P_ + (p0 + row)) * P_ + colg;
    if (colg + 4 <= P_) {
      float4 v = *(const float4*)src;
      tile[row][g * 4 + 0] = v.x;
      tile[row][g * 4 + 1] = v.y;
      tile[row][g * 4 + 2] = v.z;
      tile[row][g * 4 + 3] = v.w;
    } else {
      #pragma unroll
      for (int j = 0; j < 4; ++j)
        tile[row][g * 4 + j] = (colg + j < P_) ? src[j] : 0.f;
    }
  }
  __syncthreads();

  for (int it = t; it < 64 * 32; it += 256) {                // 64 c x 32 p-pairs
    int cl = it >> 5, pp = it & 31;
    int c = c0 + cl;
    int col = (int)rintf((float)c * step) - basea;           // < 144
    float2 val = make_float2(tile[pp * 2][col], tile[pp * 2 + 1][col]);
    *(float2*)(out3 + ((size_t)b * C_ + c) * P_ + p0 + pp * 2) = val;
  }
}

// ---------------------------------------------------------------- castE
// evec f32 [B,P,P] -> evecb bf16 [B,n,p] (straight) + evecT bf16 [B,p,n] (transposed)
__global__ __launch_bounds__(256) void castE(const float* __restrict__ evec,
                                             u16* __restrict__ evecb,
                                             u16* __restrict__ evecT) {
  const int b = blockIdx.z, n0 = blockIdx.y * 64, p0 = blockIdx.x * 64;
  __shared__ float tile[64][66];                // 264 B rows: 8B-aligned, bank step 2
  const int t = threadIdx.x;
  #pragma unroll
  for (int q = 0; q < 4; ++q) {
    int id = q * 256 + t;
    int row = id >> 4, c4 = (id & 15) * 4;
    float4 v = *(const float4*)(evec + ((size_t)b * P_ + n0 + row) * P_ + p0 + c4);
    u32 pr[2] = { pack2(v.x, v.y), pack2(v.z, v.w) };
    *(uint2*)(evecb + ((size_t)b * P_ + n0 + row) * P_ + p0 + c4) = *(uint2*)pr;
    *(float2*)&tile[row][c4]     = make_float2(v.x, v.y);
    *(float2*)&tile[row][c4 + 2] = make_float2(v.z, v.w);
  }
  __syncthreads();
  #pragma unroll
  for (int q = 0; q < 4; ++q) {
    int id = q * 256 + t;
    int pr = id >> 4, c4 = (id & 15) * 4;      // output row p-local, n-chunk
    u32 o[2];
    o[0] = pack2(tile[c4 + 0][pr], tile[c4 + 1][pr]);
    o[1] = pack2(tile[c4 + 2][pr], tile[c4 + 3][pr]);
    *(uint2*)(evecT + ((size_t)b * P_ + p0 + pr) * P_ + n0 + c4) = *(uint2*)o;
  }
}

// ---------------------------------------------------------------- castX
// x f32 [B,P,F] -> xT bf16 [B,f,n] (transposed)
__global__ __launch_bounds__(256) void castX(const float* __restrict__ x,
                                             u16* __restrict__ xT) {
  const int b = blockIdx.z, n0 = blockIdx.x * 64, f0 = blockIdx.y * 64;
  __shared__ float tile[64][66];
  const int t = threadIdx.x;
  #pragma unroll
  for (int q = 0; q < 4; ++q) {
    int id = q * 256 + t;
    int row = id >> 4, c4 = (id & 15) * 4;     // row = n-local, c4 = f-local
    float4 v = *(const float4*)(x + ((size_t)b * P_ + n0 + row) * F_ + f0 + c4);
    *(float2*)&tile[row][c4]     = make_float2(v.x, v.y);
    *(float2*)&tile[row][c4 + 2] = make_float2(v.z, v.w);
  }
  __syncthreads();
  #pragma unroll
  for (int q = 0; q < 4; ++q) {
    int id = q * 256 + t;
    int fr = id >> 4, c4 = (id & 15) * 4;      // output row f-local, n-chunk
    u32 o[2];
    o[0] = pack2(tile[c4 + 0][fr], tile[c4 + 1][fr]);
    o[1] = pack2(tile[c4 + 2][fr], tile[c4 + 3][fr]);
    *(uint2*)(xT + ((size_t)b * F_ + f0 + fr) * P_ + n0 + c4) = *(uint2*)o;
  }
}

// ---------------------------------------------------------------- shared MMA inner tile
__device__ __forceinline__ void mma_tile(const u16* lA, const u16* lB,
                                         int wm, int wn, int lrow, int quad,
                                         f32x4 acc[4][4]) {
  #pragma unroll
  for (int ks = 0; ks < 2; ++ks) {
    bf16x8 af[4], bfr[4];
    #pragma unroll
    for (int mi = 0; mi < 4; ++mi)
      af[mi] = *(const bf16x8*)(lA + swzc(wm + mi * 16 + lrow, ks * 4 + quad) * 8);
    #pragma unroll
    for (int ni = 0; ni < 4; ++ni)
      bfr[ni] = *(const bf16x8*)(lB + swzc(wn + ni * 16 + lrow, ks * 4 + quad) * 8);
    #pragma unroll
    for (int mi = 0; mi < 4; ++mi)
      #pragma unroll
      for (int ni = 0; ni < 4; ++ni)
        acc[mi][ni] = mfma16(af[mi], bfr[ni], acc[mi][ni]);
  }
}

// ---------------------------------------------------------------- GEMM1: gftT = (E^T X)^T
// C[m=f][n=p] = sum_k xT[f][k] * evecT[p][k]  (both operands k-contiguous bf16)
// Output gftT bf16 [B,F,P] in workspace (feeds GEMM2's B operand k-contiguously).
__global__ __launch_bounds__(256) void gemm1(const u16* __restrict__ xT,
                                             const u16* __restrict__ evecT,
                                             const int* __restrict__ nv,
                                             u16* __restrict__ gftT) {
  const int b = blockIdx.z, m0 = blockIdx.x * BM, p0 = blockIdx.y * BN;  // m0: f-dim
  const int N = nv[b];
  __shared__ __align__(16) u16 lA[BM * 64];
  __shared__ __align__(16) u16 lB[BN * 64];
  f32x4 acc[4][4] = {};
  const int t = threadIdx.x, lane = t & 63, w = t >> 6;
  const int wm = (w >> 1) * 64, wn = (w & 1) * 64;
  const int lrow = lane & 15, quad = lane >> 4;

  for (int kk = 0; kk < N; kk += BK) {
    #pragma unroll
    for (int q = 0; q < 4; ++q) {
      int s = q * 256 + t, m = s >> 3, csrc = (s & 7) ^ (m & 7);
      u16* ldst = lA + (q * 256 + (t & 192)) * 8;           // wave-uniform base
      gload16(xT + ((size_t)b * F_ + m0 + m) * P_ + kk + csrc * 8, ldst);
      gload16(evecT + ((size_t)b * P_ + p0 + m) * P_ + kk + csrc * 8,
              lB + (q * 256 + (t & 192)) * 8);
    }
    __syncthreads();
    mma_tile(lA, lB, wm, wn, lrow, quad, acc);
    __syncthreads();
  }

  #pragma unroll
  for (int mi = 0; mi < 4; ++mi)
    #pragma unroll
    for (int ni = 0; ni < 4; ++ni) {
      int row = m0 + wm + mi * 16 + quad * 4;               // f
      int col = p0 + wn + ni * 16 + lrow;                   // p
      u16* dst = gftT + ((size_t)b * F_ + row) * P_ + col;
      #pragma unroll
      for (int r = 0; r < 4; ++r) dst[(size_t)r * P_] = f2bf(acc[mi][ni][r]);
    }
}

// ---------------------------------------------------------------- GEMM2: U_k = E[:,lo:hi) gft[lo:hi)
// C[m=n][col=f] = sum_{k=p in [lo,hi)} evecb[n][k] * gftT[f][k]
// A always via global_load_lds (unmasked); B masked only on boundary K-tiles.
__global__ __launch_bounds__(256) void gemm2(const u16* __restrict__ evecb,
                                             const u16* __restrict__ gftT,
                                             const int* __restrict__ nv,
                                             float* __restrict__ out1) {
  const int b = blockIdx.z / 3, slab = blockIdx.z % 3;
  const int m0 = blockIdx.x * BM, f0 = blockIdx.y * BN;
  const int N = nv[b];
  const float t1 = (float)N * 0.1f;                          // match jnp f32 order
  const int s1 = (int)ceilf(t1);
  const int s2 = (int)ceilf(t1 * 2.0f);
  const int lo = (slab == 0) ? 0 : ((slab == 1) ? s1 : s1 + s2);
  const int hi = (slab == 0) ? s1 : ((slab == 1) ? s1 + s2 : N);

  __shared__ __align__(16) u16 lA[BM * 64];
  __shared__ __align__(16) u16 lB[BN * 64];
  f32x4 acc[4][4] = {};
  const int t = threadIdx.x, lane = t & 63, w = t >> 6;
  const int wm = (w >> 1) * 64, wn = (w & 1) * 64;
  const int lrow = lane & 15, quad = lane >> 4;

  for (int kk = (lo & ~(BK - 1)); kk < hi; kk += BK) {
    #pragma unroll
    for (int q = 0; q < 4; ++q) {
      int s = q * 256 + t, m = s >> 3, csrc = (s & 7) ^ (m & 7);
      gload16(evecb + ((size_t)b * P_ + m0 + m) * P_ + kk + csrc * 8,
              lA + (q * 256 + (t & 192)) * 8);
    }
    if (kk >= lo && kk + BK <= hi) {                         // interior: fast path
      #pragma unroll
      for (int q = 0; q < 4; ++q) {
        int s = q * 256 + t, m = s >> 3, csrc = (s & 7) ^ (m & 7);
        gload16(gftT + ((size_t)b * F_ + f0 + m) * P_ + kk + csrc * 8,
                lB + (q * 256 + (t & 192)) * 8);
      }
    } else {                                                 // boundary: masked reg path
      #pragma unroll
      for (int q = 0; q < 4; ++q) {
        int s = q * 256 + t, m = s >> 3, c = s & 7;
        int kb = kk + c * 8;
        U4 u;
        u.v = *(const uint4*)(gftT + ((size_t)b * F_ + f0 + m) * P_ + kb);
        if (kb < lo || kb + 8 > hi) {
          #pragma unroll
          for (int j = 0; j < 8; ++j)
            if (kb + j < lo || kb + j >= hi) u.h[j] = 0;
        }
        *(uint4*)(lB + swzc(m, c) * 8) = u.v;
      }
    }
    __syncthreads();
    mma_tile(lA, lB, wm, wn, lrow, quad, acc);
    __syncthreads();
  }

  #pragma unroll
  for (int mi = 0; mi < 4; ++mi)
    #pragma unroll
    for (int ni = 0; ni < 4; ++ni) {
      int row = m0 + wm + mi * 16 + quad * 4;               // n
      int col = f0 + wn + ni * 16 + lrow;                   // f
      float* dst = out1 + (((size_t)b * 3 + slab) * P_ + row) * F_ + col;
      #pragma unroll
      for (int r = 0; r < 4; ++r) dst[(size_t)r * F_] = acc[mi][ni][r];
    }
}

// ----------------------------------------------------------------
extern "C" void kernel_launch(void* const* d_in, const int* in_sizes, int n_in,
                              void* d_out, int out_size, void* d_ws, size_t ws_size,
                              hipStream_t stream) {
  const float* x  = nullptr;   // f32 [B,P,F]
  const float* ev = nullptr;   // f32 [B,P,P]
  const int*   nv = nullptr;   // i32 [B]
  for (int i = 0; i < n_in; ++i) {
    if      (in_sizes[i] == B_)            nv = (const int*)d_in[i];
    else if (in_sizes[i] == B_ * P_ * P_)  ev = (const float*)d_in[i];
    else if (in_sizes[i] == B_ * P_ * F_)  x  = (const float*)d_in[i];
  }

  float* out = (float*)d_out;              // f32 outputs, concatenated flat
  const size_t S0 = (size_t)B_ * P_ * F_;  // 16,777,216
  float* out0 = out;                       // n_level_feat    [B,P,F]
  float* out1 = out + S0;                  // x_updated       [B,3,P,F]
  float* out2 = out + 4 * S0;              // original_x      [B,3,P,F]
  float* out3 = out + 7 * S0;              // updated_evectors[B,C,P]

  // workspace (bf16): gftT[B,F,P] | evecT[B,P,P] | evecb[B,P,P] | xT[B,F,P]  (~201 MB)
  u16* gftT  = (u16*)d_ws;
  u16* evecT = gftT  + (size_t)B_ * F_ * P_;
  u16* evecb = evecT + (size_t)B_ * P_ * P_;
  u16* xT    = evecb + (size_t)B_ * P_ * P_;

  copy_kernel<<<16384, 256, 0, stream>>>((const uint4*)x, (uint4*)out0, (uint4*)out2);
  sel_kernel<<<dim3(16, 8, 32), 256, 0, stream>>>(ev, nv, out3);
  castX<<<dim3(16, 8, 32), 256, 0, stream>>>(x, xT);
  castE<<<dim3(16, 16, 32), 256, 0, stream>>>(ev, evecb, evecT);
  gemm1<<<dim3(4, 8, 32), 256, 0, stream>>>(xT, evecT, nv, gftT);
  gemm2<<<dim3(8, 4, 96), 256, 0, stream>>>(evecb, gftT, nv, out1);
}

// Round 2
// 795.418 us; speedup vs baseline: 1.2716x; 1.0345x over previous
//
#include <hip/hip_runtime.h>
#include <hip/hip_bf16.h>

#define B_ 32
#define P_ 1024
#define F_ 512
#define C_ 512

#define BM 128
#define BN 128
#define BK 64

typedef unsigned short u16;
typedef unsigned int   u32;
typedef __bf16 bf16x8 __attribute__((ext_vector_type(8)));
typedef float  f32x4  __attribute__((ext_vector_type(4)));

union U4 { uint4 v; u16 h[8]; u32 w[4]; };

__device__ __forceinline__ u16 f2bf(float f) {
  u32 x = __builtin_bit_cast(u32, f);
  return (u16)((x + 0x7FFFu + ((x >> 16) & 1u)) >> 16);   // RNE
}
__device__ __forceinline__ u32 pack2(float a, float b) {
  return (u32)f2bf(a) | ((u32)f2bf(b) << 16);
}
__device__ __forceinline__ float bf2f(u16 h) {
  u32 x = (u32)h << 16;
  return __builtin_bit_cast(float, x);
}

__device__ __forceinline__ f32x4 mfma16(bf16x8 a, bf16x8 b, f32x4 c) {
  return __builtin_amdgcn_mfma_f32_16x16x32_bf16(a, b, c, 0, 0, 0);
}

// 16B-chunk XOR swizzle for a [rows][64] bf16 tile: logical chunk c of row m lives
// at chunk m*8 + (c ^ (m&7)).  Spreads fragment reads (16 rows, same c) over all banks.
__device__ __forceinline__ int swzc(int m, int c) { return m * 8 + (c ^ (m & 7)); }

// async global->LDS, 16 B per lane; dest = wave-uniform base + lane*16
__device__ __forceinline__ void gload16(const u16* g, u16* l) {
  __builtin_amdgcn_global_load_lds((const __attribute__((address_space(1))) void*)(g),
                                   (__attribute__((address_space(3))) void*)(l), 16, 0, 0);
}

// ---------------------------------------------------------------- castE
// evec f32 [B,P,P] -> evecb bf16 [B,n,p] (straight) + evecT bf16 [B,p,n] (transposed)
__global__ __launch_bounds__(256) void castE(const float* __restrict__ evec,
                                             u16* __restrict__ evecb,
                                             u16* __restrict__ evecT) {
  const int b = blockIdx.z, n0 = blockIdx.y * 64, p0 = blockIdx.x * 64;
  __shared__ float tile[64][66];
  const int t = threadIdx.x;
  #pragma unroll
  for (int q = 0; q < 4; ++q) {
    int id = q * 256 + t;
    int row = id >> 4, c4 = (id & 15) * 4;
    float4 v = *(const float4*)(evec + ((size_t)b * P_ + n0 + row) * P_ + p0 + c4);
    u32 pr[2] = { pack2(v.x, v.y), pack2(v.z, v.w) };
    *(uint2*)(evecb + ((size_t)b * P_ + n0 + row) * P_ + p0 + c4) = *(uint2*)pr;
    *(float2*)&tile[row][c4]     = make_float2(v.x, v.y);
    *(float2*)&tile[row][c4 + 2] = make_float2(v.z, v.w);
  }
  __syncthreads();
  #pragma unroll
  for (int q = 0; q < 4; ++q) {
    int id = q * 256 + t;
    int pr = id >> 4, c4 = (id & 15) * 4;
    u32 o[2];
    o[0] = pack2(tile[c4 + 0][pr], tile[c4 + 1][pr]);
    o[1] = pack2(tile[c4 + 2][pr], tile[c4 + 3][pr]);
    *(uint2*)(evecT + ((size_t)b * P_ + p0 + pr) * P_ + n0 + c4) = *(uint2*)o;
  }
}

// ---------------------------------------------------------------- castX + copy fusion
// x f32 [B,P,F] -> out0 (copy), out2 (3x broadcast), xT bf16 [B,f,n] (transposed)
__global__ __launch_bounds__(256) void castX_copy(const float* __restrict__ x,
                                                  u16* __restrict__ xT,
                                                  float* __restrict__ out0,
                                                  float* __restrict__ out2) {
  const int b = blockIdx.z, n0 = blockIdx.x * 64, f0 = blockIdx.y * 64;
  __shared__ float tile[64][66];
  const int t = threadIdx.x;
  #pragma unroll
  for (int q = 0; q < 4; ++q) {
    int id = q * 256 + t;
    int row = id >> 4, c4 = (id & 15) * 4;
    size_t src = ((size_t)b * P_ + n0 + row) * F_ + f0 + c4;
    float4 v = *(const float4*)(x + src);
    *(float4*)(out0 + src) = v;
    size_t d2 = (((size_t)b * 3) * P_ + n0 + row) * F_ + f0 + c4;
    *(float4*)(out2 + d2) = v;
    *(float4*)(out2 + d2 + (size_t)P_ * F_) = v;
    *(float4*)(out2 + d2 + 2 * (size_t)P_ * F_) = v;
    *(float2*)&tile[row][c4]     = make_float2(v.x, v.y);
    *(float2*)&tile[row][c4 + 2] = make_float2(v.z, v.w);
  }
  __syncthreads();
  #pragma unroll
  for (int q = 0; q < 4; ++q) {
    int id = q * 256 + t;
    int fr = id >> 4, c4 = (id & 15) * 4;
    u32 o[2];
    o[0] = pack2(tile[c4 + 0][fr], tile[c4 + 1][fr]);
    o[1] = pack2(tile[c4 + 2][fr], tile[c4 + 3][fr]);
    *(uint2*)(xT + ((size_t)b * F_ + f0 + fr) * P_ + n0 + c4) = *(uint2*)o;
  }
}

// ---------------------------------------------------------------- out3 row-gather
// out3[b,c,:] = f32(evecT[b, round(c*step), :])  -- coalesced 2KB row copies
__global__ __launch_bounds__(256) void sel_kernel(const u16* __restrict__ evecT,
                                                  const int* __restrict__ nv,
                                                  float* __restrict__ out3) {
  const int b = blockIdx.y, c0 = blockIdx.x * 4, t = threadIdx.x;
  const int N = nv[b];
  const float step = (float)(N - 1) / 511.0f;
  #pragma unroll
  for (int r = 0; r < 4; ++r) {
    int c = c0 + r;
    int idx = (int)rintf((float)c * step);
    uint2 v = *(const uint2*)(evecT + ((size_t)b * P_ + idx) * P_ + t * 4);
    float4 o;
    o.x = bf2f((u16)(v.x & 0xffffu)); o.y = bf2f((u16)(v.x >> 16));
    o.z = bf2f((u16)(v.y & 0xffffu)); o.w = bf2f((u16)(v.y >> 16));
    *(float4*)(out3 + ((size_t)b * C_ + c) * P_ + t * 4) = o;
  }
}

// ---------------------------------------------------------------- shared MMA inner tile
__device__ __forceinline__ void mma_tile(const u16* lA, const u16* lB,
                                         int wm, int wn, int lrow, int quad,
                                         f32x4 acc[4][4]) {
  #pragma unroll
  for (int ks = 0; ks < 2; ++ks) {
    bf16x8 af[4], bfr[4];
    #pragma unroll
    for (int mi = 0; mi < 4; ++mi)
      af[mi] = *(const bf16x8*)(lA + swzc(wm + mi * 16 + lrow, ks * 4 + quad) * 8);
    #pragma unroll
    for (int ni = 0; ni < 4; ++ni)
      bfr[ni] = *(const bf16x8*)(lB + swzc(wn + ni * 16 + lrow, ks * 4 + quad) * 8);
    #pragma unroll
    for (int mi = 0; mi < 4; ++mi)
      #pragma unroll
      for (int ni = 0; ni < 4; ++ni)
        acc[mi][ni] = mfma16(af[mi], bfr[ni], acc[mi][ni]);
  }
}

// stage one 128x64 tile pair via global_load_lds (rows m at stride P_, cols kk..kk+63)
__device__ __forceinline__ void stage2(const u16* gA, const u16* gB,
                                       u16* lA, u16* lB, int t) {
  #pragma unroll
  for (int q = 0; q < 4; ++q) {
    int s = q * 256 + t, m = s >> 3, csrc = (s & 7) ^ (m & 7);
    gload16(gA + (size_t)m * P_ + csrc * 8, lA + (q * 256 + (t & 192)) * 8);
    gload16(gB + (size_t)m * P_ + csrc * 8, lB + (q * 256 + (t & 192)) * 8);
  }
}
__device__ __forceinline__ void stage1op(const u16* g, u16* l, int t) {
  #pragma unroll
  for (int q = 0; q < 4; ++q) {
    int s = q * 256 + t, m = s >> 3, csrc = (s & 7) ^ (m & 7);
    gload16(g + (size_t)m * P_ + csrc * 8, l + (q * 256 + (t & 192)) * 8);
  }
}

// ---------------------------------------------------------------- GEMM1: gftT = (E^T X)^T
// C[m=f][n=p] = sum_k xT[f][k] * evecT[p][k], 2-phase double-buffered staging.
__global__ __launch_bounds__(256) void gemm1(const u16* __restrict__ xT,
                                             const u16* __restrict__ evecT,
                                             const int* __restrict__ nv,
                                             u16* __restrict__ gftT) {
  const int b = blockIdx.z, m0 = blockIdx.x * BM, p0 = blockIdx.y * BN;
  const int N = nv[b];
  __shared__ __align__(16) u16 lA[2][BM * BK];
  __shared__ __align__(16) u16 lB[2][BN * BK];
  f32x4 acc[4][4] = {};
  const int t = threadIdx.x, lane = t & 63, w = t >> 6;
  const int wm = (w >> 1) * 64, wn = (w & 1) * 64;
  const int lrow = lane & 15, quad = lane >> 4;
  const u16* gA = xT + ((size_t)b * F_ + m0) * P_;
  const u16* gB = evecT + ((size_t)b * P_ + p0) * P_;
  const int nt = (N + BK - 1) / BK;

  stage2(gA, gB, lA[0], lB[0], t);
  __syncthreads();
  int cur = 0;
  for (int ti = 0; ti < nt; ++ti) {
    if (ti + 1 < nt)
      stage2(gA + (ti + 1) * BK, gB + (ti + 1) * BK, lA[cur ^ 1], lB[cur ^ 1], t);
    mma_tile(lA[cur], lB[cur], wm, wn, lrow, quad, acc);
    __syncthreads();
    cur ^= 1;
  }

  #pragma unroll
  for (int mi = 0; mi < 4; ++mi)
    #pragma unroll
    for (int ni = 0; ni < 4; ++ni) {
      int row = m0 + wm + mi * 16 + quad * 4;               // f
      int col = p0 + wn + ni * 16 + lrow;                   // p
      u16* dst = gftT + ((size_t)b * F_ + row) * P_ + col;
      #pragma unroll
      for (int r = 0; r < 4; ++r) dst[(size_t)r * P_] = f2bf(acc[mi][ni][r]);
    }
}

// ---------------------------------------------------------------- GEMM2: U_k = E[:,lo:hi) gft[lo:hi)
// C[m=n][col=f] = sum_{k in [lo,hi)} evecb[n][k] * gftT[f][k], 2-phase double-buffered.
// Boundary K-tiles: T14 split (global->reg+mask before MFMA, ds_write after).
__global__ __launch_bounds__(256) void gemm2(const u16* __restrict__ evecb,
                                             const u16* __restrict__ gftT,
                                             const int* __restrict__ nv,
                                             float* __restrict__ out1) {
  const int b = blockIdx.z / 3, slab = blockIdx.z % 3;
  const int m0 = blockIdx.x * BM, f0 = blockIdx.y * BN;
  const int N = nv[b];
  const float t1 = (float)N * 0.1f;                          // match jnp f32 order
  const int s1 = (int)ceilf(t1);
  const int s2 = (int)ceilf(t1 * 2.0f);
  const int lo = (slab == 0) ? 0 : ((slab == 1) ? s1 : s1 + s2);
  const int hi = (slab == 0) ? s1 : ((slab == 1) ? s1 + s2 : N);

  __shared__ __align__(16) u16 lA[2][BM * BK];
  __shared__ __align__(16) u16 lB[2][BN * BK];
  f32x4 acc[4][4] = {};
  const int t = threadIdx.x, lane = t & 63, w = t >> 6;
  const int wm = (w >> 1) * 64, wn = (w & 1) * 64;
  const int lrow = lane & 15, quad = lane >> 4;
  const u16* gA = evecb + ((size_t)b * P_ + m0) * P_;
  const u16* gB = gftT + ((size_t)b * F_ + f0) * P_;
  const int kstart = lo & ~(BK - 1);
  const int nt = (hi - kstart + BK - 1) / BK;

  // prologue: stage tile 0
  {
    stage1op(gA + kstart, lA[0], t);
    if (kstart >= lo && kstart + BK <= hi) {
      stage1op(gB + kstart, lB[0], t);
    } else {
      #pragma unroll
      for (int q = 0; q < 4; ++q) {
        int s = q * 256 + t, m = s >> 3, c = s & 7;
        int kb = kstart + c * 8;
        U4 u; u.v = *(const uint4*)(gB + (size_t)m * P_ + kb);
        #pragma unroll
        for (int j = 0; j < 8; ++j)
          if (kb + j < lo || kb + j >= hi) u.h[j] = 0;
        *(uint4*)(lB[0] + swzc(m, c) * 8) = u.v;
      }
    }
  }
  __syncthreads();

  int cur = 0;
  for (int ti = 0; ti < nt; ++ti) {
    const int kn = kstart + (ti + 1) * BK;
    const bool have = (ti + 1 < nt);
    bool nb = false;
    U4 breg[4];
    if (have) {
      stage1op(gA + kn, lA[cur ^ 1], t);
      nb = !(kn >= lo && kn + BK <= hi);
      if (!nb) {
        stage1op(gB + kn, lB[cur ^ 1], t);
      } else {
        #pragma unroll
        for (int q = 0; q < 4; ++q) {
          int s = q * 256 + t, m = s >> 3, c = s & 7;
          int kb = kn + c * 8;
          breg[q].v = *(const uint4*)(gB + (size_t)m * P_ + kb);
          #pragma unroll
          for (int j = 0; j < 8; ++j)
            if (kb + j < lo || kb + j >= hi) breg[q].h[j] = 0;
        }
      }
    }
    mma_tile(lA[cur], lB[cur], wm, wn, lrow, quad, acc);
    if (have && nb) {
      #pragma unroll
      for (int q = 0; q < 4; ++q) {
        int s = q * 256 + t, m = s >> 3, c = s & 7;
        *(uint4*)(lB[cur ^ 1] + swzc(m, c) * 8) = breg[q].v;
      }
    }
    __syncthreads();
    cur ^= 1;
  }

  #pragma unroll
  for (int mi = 0; mi < 4; ++mi)
    #pragma unroll
    for (int ni = 0; ni < 4; ++ni) {
      int row = m0 + wm + mi * 16 + quad * 4;               // n
      int col = f0 + wn + ni * 16 + lrow;                   // f
      float* dst = out1 + (((size_t)b * 3 + slab) * P_ + row) * F_ + col;
      #pragma unroll
      for (int r = 0; r < 4; ++r) dst[(size_t)r * F_] = acc[mi][ni][r];
    }
}

// ----------------------------------------------------------------
extern "C" void kernel_launch(void* const* d_in, const int* in_sizes, int n_in,
                              void* d_out, int out_size, void* d_ws, size_t ws_size,
                              hipStream_t stream) {
  const float* x  = nullptr;   // f32 [B,P,F]
  const float* ev = nullptr;   // f32 [B,P,P]
  const int*   nv = nullptr;   // i32 [B]
  for (int i = 0; i < n_in; ++i) {
    if      (in_sizes[i] == B_)            nv = (const int*)d_in[i];
    else if (in_sizes[i] == B_ * P_ * P_)  ev = (const float*)d_in[i];
    else if (in_sizes[i] == B_ * P_ * F_)  x  = (const float*)d_in[i];
  }

  float* out = (float*)d_out;              // f32 outputs, concatenated flat
  const size_t S0 = (size_t)B_ * P_ * F_;  // 16,777,216
  float* out0 = out;                       // n_level_feat    [B,P,F]
  float* out1 = out + S0;                  // x_updated       [B,3,P,F]
  float* out2 = out + 4 * S0;              // original_x      [B,3,P,F]
  float* out3 = out + 7 * S0;              // updated_evectors[B,C,P]

  // workspace (bf16): gftT[B,F,P] | evecT[B,P,P] | evecb[B,P,P] | xT[B,F,P]  (~201 MB)
  u16* gftT  = (u16*)d_ws;
  u16* evecT = gftT  + (size_t)B_ * F_ * P_;
  u16* evecb = evecT + (size_t)B_ * P_ * P_;
  u16* xT    = evecb + (size_t)B_ * P_ * P_;

  castE<<<dim3(16, 16, 32), 256, 0, stream>>>(ev, evecb, evecT);
  castX_copy<<<dim3(16, 8, 32), 256, 0, stream>>>(x, xT, out0, out2);
  sel_kernel<<<dim3(128, 32), 256, 0, stream>>>(evecT, nv, out3);
  gemm1<<<dim3(4, 8, 32), 256, 0, stream>>>(xT, evecT, nv, gftT);
  gemm2<<<dim3(8, 4, 96), 256, 0, stream>>>(evecb, gftT, nv, out1);
}